// Round 11
// baseline (495.210 us; speedup 1.0000x reference)
//
#include <hip/hip_runtime.h>
#include <hip/hip_bf16.h>

typedef unsigned short u16;
typedef __bf16 bf16x8 __attribute__((ext_vector_type(8)));
typedef u16 u16x4 __attribute__((ext_vector_type(4)));
typedef u16 u16x8 __attribute__((ext_vector_type(8)));
typedef float f32x4 __attribute__((ext_vector_type(4)));

#define S_LEN  2048
#define HID    4096
#define NHEADS 32
#define NKV    8
#define HD     128
#define QDIM   (NHEADS*HD)   // 4096
#define KVDIM  (NKV*HD)      // 1024
#define NT     (S_LEN/64)    // 32 kv/q tiles

__device__ __forceinline__ u16 f2bf(float f) {
  unsigned u = __float_as_uint(f);
  u += 0x7fff + ((u >> 16) & 1);   // RNE
  return (u16)(u >> 16);
}
__device__ __forceinline__ void lds_load16(const u16* g, u16* l) {
  __builtin_amdgcn_global_load_lds(
      (__attribute__((address_space(1))) void*)(g),
      (__attribute__((address_space(3))) void*)(l), 16, 0, 0);
}

// ---------------------------------------------------------------------------
// Segmented fp32 -> bf16 bulk convert: 4 buffers in one launch. n = elems/8.
// ---------------------------------------------------------------------------
__global__ __launch_bounds__(256) void f2b4(
    const float* __restrict__ s0, u16* __restrict__ d0, long n0,
    const float* __restrict__ s1, u16* __restrict__ d1, long n1,
    const float* __restrict__ s2, u16* __restrict__ d2, long n2,
    const float* __restrict__ s3, u16* __restrict__ d3, long n3)
{
  const float* s; u16* d; long n; int b0, nb;
  const int b = blockIdx.x;
  if (b < 1024)      { s=s0; d=d0; n=n0; b0=0;    nb=1024; }
  else if (b < 3072) { s=s1; d=d1; n=n1; b0=1024; nb=2048; }
  else if (b < 3584) { s=s2; d=d2; n=n2; b0=3072; nb=512;  }
  else               { s=s3; d=d3; n=n3; b0=3584; nb=512;  }
  long i = (long)(b - b0)*256 + threadIdx.x;
  const long stride = (long)nb*256;
  for (; i < n; i += stride) {
    f32x4 a = ((const f32x4*)s)[i*2];
    f32x4 c = ((const f32x4*)s)[i*2 + 1];
    u16x8 o;
    #pragma unroll
    for (int j = 0; j < 4; ++j) { o[j] = f2bf(a[j]); o[4+j] = f2bf(c[j]); }
    ((u16x8*)d)[i] = o;
  }
}

__global__ __launch_bounds__(256) void f2b(
    const float* __restrict__ in, u16* __restrict__ out, long n8)
{
  long i = (long)blockIdx.x * blockDim.x + threadIdx.x;
  const long stride = (long)gridDim.x * blockDim.x;
  for (; i < n8; i += stride) {
    f32x4 a = ((const f32x4*)in)[i*2];
    f32x4 b = ((const f32x4*)in)[i*2 + 1];
    u16x8 o;
    #pragma unroll
    for (int j = 0; j < 4; ++j) { o[j] = f2bf(a[j]); o[4+j] = f2bf(b[j]); }
    ((u16x8*)out)[i] = o;
  }
}

// ---------------------------------------------------------------------------
// QKV projection GEMM: 256x192 tile -> grid 32x8 = 256 blocks (verified r6-10).
// ---------------------------------------------------------------------------
template<int K>
__global__ __launch_bounds__(512, 2) void gemmQ(
    const u16* __restrict__ A, const u16* __restrict__ B,
    u16* __restrict__ Cq, u16* __restrict__ Ck, u16* __restrict__ Cv)
{
  __shared__ u16 lds[57344];   // A: [0,32768) 2x16384; B: [32768,57344) 2x12288
  const int tid  = threadIdx.x;
  const int lane = tid & 63;
  const int w    = tid >> 6;
  const int wr   = w >> 2, wc = w & 3;
  const int l16  = lane & 15, lhi = lane >> 4;
  const long arow0 = (long)blockIdx.y * 256;
  const long brow0 = (long)blockIdx.x * 192;
  const int ntiles = K >> 6;

  const int cu = ((lane & 7) ^ (lane >> 3)) * 8;
  const int wl = w*8 + (lane >> 3);
  const u16* Ag[4];
  #pragma unroll
  for (int r = 0; r < 4; ++r)
    Ag[r] = A + (arow0 + r*64 + wl)*(long)K + cu;
  const u16* Bg[3];
  #pragma unroll
  for (int r = 0; r < 2; ++r) {
    const int rp = r*64 + wl;
    Bg[r] = B + (brow0 + (rp >> 5)*48 + (rp & 31))*(long)K + cu;
  }
  Bg[2] = B + (brow0 + (wl >> 4)*48 + 32 + (wl & 15))*(long)K + cu;

  auto stageA = [&](int s, int kt) {
    u16* d = lds + ((kt & 1) << 14) + w*512;
    lds_load16(Ag[s]   + (long)kt*64, d + s*4096);
    lds_load16(Ag[s+2] + (long)kt*64, d + (s+2)*4096);
  };
  auto stageB0 = [&](int kt) {
    u16* d = lds + 32768 + (kt & 1)*12288 + w*512;
    lds_load16(Bg[0] + (long)kt*64, d);
    lds_load16(Bg[1] + (long)kt*64, d + 4096);
  };
  auto stageB1 = [&](int kt) {
    u16* d = lds + 32768 + (kt & 1)*12288 + w*512;
    lds_load16(Bg[2] + (long)kt*64, d + 8192);
  };

  const int xr = (l16 & 7) << 3;
  int offA[4][2], offB[2][2], offB2[2];
  #pragma unroll
  for (int m2 = 0; m2 < 4; ++m2)
    #pragma unroll
    for (int ks = 0; ks < 2; ++ks)
      offA[m2][ks] = (wr*128 + m2*16 + l16)*64 + ((ks*32 + lhi*8) ^ xr);
  #pragma unroll
  for (int n2 = 0; n2 < 2; ++n2)
    #pragma unroll
    for (int ks = 0; ks < 2; ++ks)
      offB[n2][ks] = (wc*32 + n2*16 + l16)*64 + ((ks*32 + lhi*8) ^ xr);
  #pragma unroll
  for (int ks = 0; ks < 2; ++ks)
    offB2[ks] = 8192 + (wc*16 + l16)*64 + ((ks*32 + lhi*8) ^ xr);

  f32x4 acc[8][3] = {};

  stageA(0, 0); stageB0(0); stageB1(0); stageA(1, 0);
  stageA(0, 1); stageB0(1); stageB1(1);
  asm volatile("s_waitcnt vmcnt(5)" ::: "memory");
  __builtin_amdgcn_s_barrier();

  #pragma unroll 2
  for (int t = 0; t < ntiles; ++t) {
    const int Ab = (t & 1) << 14;
    const int Bb = 32768 + (t & 1)*12288;
    bf16x8 af[4][2], af2[4][2], bf[2][2], bf2[2];

    // ---------- phase 1: A half0 x B part0 -> acc[0:4][0:2] ----------
    #pragma unroll
    for (int m2 = 0; m2 < 4; ++m2)
      #pragma unroll
      for (int ks = 0; ks < 2; ++ks)
        af[m2][ks] = *(const bf16x8*)(lds + Ab + offA[m2][ks]);
    #pragma unroll
    for (int n2 = 0; n2 < 2; ++n2)
      #pragma unroll
      for (int ks = 0; ks < 2; ++ks)
        bf[n2][ks] = *(const bf16x8*)(lds + Bb + offB[n2][ks]);
    if (t + 1 < ntiles) stageA(1, t + 1);
    __builtin_amdgcn_s_barrier();
    asm volatile("s_waitcnt lgkmcnt(0)" ::: "memory");
    __builtin_amdgcn_s_setprio(1);
    #pragma unroll
    for (int m2 = 0; m2 < 4; ++m2)
      #pragma unroll
      for (int n2 = 0; n2 < 2; ++n2)
        #pragma unroll
        for (int ks = 0; ks < 2; ++ks)
          acc[m2][n2] = __builtin_amdgcn_mfma_f32_16x16x32_bf16(
              af[m2][ks], bf[n2][ks], acc[m2][n2], 0, 0, 0);
    __builtin_amdgcn_s_setprio(0);
    __builtin_amdgcn_s_barrier();

    // ---------- phase 2: A half0 x B part1 -> acc[0:4][2] ----------
    #pragma unroll
    for (int ks = 0; ks < 2; ++ks)
      bf2[ks] = *(const bf16x8*)(lds + Bb + offB2[ks]);
    if (t + 2 < ntiles) stageA(0, t + 2);
    __builtin_amdgcn_s_barrier();
    asm volatile("s_waitcnt lgkmcnt(0)" ::: "memory");
    __builtin_amdgcn_s_setprio(1);
    #pragma unroll
    for (int m2 = 0; m2 < 4; ++m2)
      #pragma unroll
      for (int ks = 0; ks < 2; ++ks)
        acc[m2][2] = __builtin_amdgcn_mfma_f32_16x16x32_bf16(
            af[m2][ks], bf2[ks], acc[m2][2], 0, 0, 0);
    __builtin_amdgcn_s_setprio(0);
    __builtin_amdgcn_s_barrier();

    // ---------- phase 3: A half1 x B part1 -> acc[4:8][2] ----------
    #pragma unroll
    for (int m2 = 0; m2 < 4; ++m2)
      #pragma unroll
      for (int ks = 0; ks < 2; ++ks)
        af2[m2][ks] = *(const bf16x8*)(lds + Ab + 4096 + offA[m2][ks]);
    if (t + 2 < ntiles) stageB0(t + 2);
    __builtin_amdgcn_s_barrier();
    asm volatile("s_waitcnt lgkmcnt(0)" ::: "memory");
    __builtin_amdgcn_s_setprio(1);
    #pragma unroll
    for (int m2 = 0; m2 < 4; ++m2)
      #pragma unroll
      for (int ks = 0; ks < 2; ++ks)
        acc[4+m2][2] = __builtin_amdgcn_mfma_f32_16x16x32_bf16(
            af2[m2][ks], bf2[ks], acc[4+m2][2], 0, 0, 0);
    __builtin_amdgcn_s_setprio(0);
    __builtin_amdgcn_s_barrier();

    // ---------- phase 4: A half1 x B part0 -> acc[4:8][0:2] ----------
    if (t + 2 < ntiles) stageB1(t + 2);
    __builtin_amdgcn_s_barrier();
    __builtin_amdgcn_s_setprio(1);
    #pragma unroll
    for (int m2 = 0; m2 < 4; ++m2)
      #pragma unroll
      for (int n2 = 0; n2 < 2; ++n2)
        #pragma unroll
        for (int ks = 0; ks < 2; ++ks)
          acc[4+m2][n2] = __builtin_amdgcn_mfma_f32_16x16x32_bf16(
              af2[m2][ks], bf[n2][ks], acc[4+m2][n2], 0, 0, 0);
    __builtin_amdgcn_s_setprio(0);
    if (t + 2 < ntiles) { asm volatile("s_waitcnt vmcnt(5)" ::: "memory"); }
    else                { asm volatile("s_waitcnt vmcnt(0)" ::: "memory"); }
    __builtin_amdgcn_s_barrier();
  }

  #pragma unroll
  for (int m = 0; m < 8; ++m) {
    const long row = arow0 + wr*128 + (m >> 2)*64 + (m & 3)*16 + lhi*4;
    #pragma unroll
    for (int n = 0; n < 3; ++n) {
      const long col = brow0 + wc*48 + n*16 + l16;
      if (col < QDIM) {
        #pragma unroll
        for (int r = 0; r < 4; ++r)
          Cq[(row + r)*QDIM + col] = f2bf(acc[m][n][r]);
      } else if (col < QDIM + KVDIM) {
        #pragma unroll
        for (int r = 0; r < 4; ++r)
          Ck[(row + r)*KVDIM + (col - QDIM)] = f2bf(acc[m][n][r]);
      } else {
        u16x4 o;
        #pragma unroll
        for (int r = 0; r < 4; ++r) o[r] = f2bf(acc[m][n][r]);
        *(u16x4*)(Cv + (col - QDIM - KVDIM)*(long)S_LEN + row) = o;
      }
    }
  }
}

// ---------------------------------------------------------------------------
// 128x256-tile 4-phase GEMM for the final projection (verified rounds 2-10).
// ---------------------------------------------------------------------------
template<int N, int K>
__global__ __launch_bounds__(512, 2) void gemmF(
    const u16* __restrict__ A, const u16* __restrict__ B,
    float* __restrict__ C)
{
  __shared__ u16 lds[49152];   // A: [0,16384) 2x8192; B: [16384,49152) 2x16384
  const int tid  = threadIdx.x;
  const int lane = tid & 63;
  const int w    = tid >> 6;
  const int wr   = w >> 2, wc = w & 3;
  const int l16  = lane & 15, lhi = lane >> 4;
  const long arow0 = (long)blockIdx.y * 128;
  const long brow0 = (long)blockIdx.x * 256;
  const int ntiles = K >> 6;

  const int cu = ((lane & 7) ^ (lane >> 3)) * 8;
  const int rA  = (w >> 2)*64 + (w & 3)*8;
  const int rB1c = 128 + (w >> 2)*64 + (w & 3)*8;
  const u16* srcA  = A + (arow0 + rA   + (lane >> 3))*(long)K + cu;
  const u16* srcB0 = B + (brow0 + rA   + (lane >> 3))*(long)K + cu;
  const u16* srcB1 = B + (brow0 + rB1c + (lane >> 3))*(long)K + cu;
  u16* const dA  = lds + rA*64;
  u16* const dB0 = lds + 16384 + rA*64;
  u16* const dB1 = lds + 16384 + rB1c*64;

  auto stageA = [&](int s, int kt) {
    lds_load16(srcA + (long)(s*32)*K + kt*64,
               dA + ((kt & 1) << 13) + s*2048);
  };
  auto stageB = [&](int s, int kt) {
    const long so = (long)(s*32)*K + kt*64;
    const int  d  = ((kt & 1) << 14) + s*2048;
    lds_load16(srcB0 + so, dB0 + d);
    lds_load16(srcB1 + so, dB1 + d);
  };

  const int xr = (l16 & 7) << 3;
  int offA[2][2], offB[2][2];
  #pragma unroll
  for (int m = 0; m < 2; ++m)
    #pragma unroll
    for (int ks = 0; ks < 2; ++ks)
      offA[m][ks] = (wr*64 + m*16 + l16)*64 + ((ks*32 + lhi*8) ^ xr);
  #pragma unroll
  for (int n = 0; n < 2; ++n)
    #pragma unroll
    for (int ks = 0; ks < 2; ++ks)
      offB[n][ks] = (wc*64 + n*16 + l16)*64 + ((ks*32 + lhi*8) ^ xr);

  f32x4 acc[4][4] = {};

  stageA(0, 0); stageA(1, 0); stageB(0, 0); stageB(1, 0);
  if (ntiles > 1) { stageA(0, 1); stageB(0, 1); stageB(1, 1); }
  asm volatile("s_waitcnt vmcnt(5)" ::: "memory");
  __builtin_amdgcn_s_barrier();

  #pragma unroll 2
  for (int t = 0; t < ntiles; ++t) {
    const int Ab = (t & 1) << 13;
    const int Bb = 16384 + ((t & 1) << 14);
    bf16x8 af[2][2], bf[2][2], af2[2][2], bf2[2][2];

    // ---------- phase 1 ----------
    #pragma unroll
    for (int m = 0; m < 2; ++m)
      #pragma unroll
      for (int ks = 0; ks < 2; ++ks)
        af[m][ks] = *(const bf16x8*)(lds + Ab + offA[m][ks]);
    #pragma unroll
    for (int n = 0; n < 2; ++n)
      #pragma unroll
      for (int ks = 0; ks < 2; ++ks)
        bf[n][ks] = *(const bf16x8*)(lds + Bb + offB[n][ks]);
    if (t + 1 < ntiles) stageA(1, t + 1);
    __builtin_amdgcn_s_barrier();
    asm volatile("s_waitcnt lgkmcnt(0)" ::: "memory");
    __builtin_amdgcn_s_setprio(1);
    #pragma unroll
    for (int m = 0; m < 2; ++m)
      #pragma unroll
      for (int n = 0; n < 2; ++n)
        #pragma unroll
        for (int ks = 0; ks < 2; ++ks)
          acc[m][n] = __builtin_amdgcn_mfma_f32_16x16x32_bf16(
              af[m][ks], bf[n][ks], acc[m][n], 0, 0, 0);
    __builtin_amdgcn_s_setprio(0);
    __builtin_amdgcn_s_barrier();

    // ---------- phase 2 ----------
    #pragma unroll
    for (int n = 0; n < 2; ++n)
      #pragma unroll
      for (int ks = 0; ks < 2; ++ks)
        bf2[n][ks] = *(const bf16x8*)(lds + Bb + 2048 + offB[n][ks]);
    if (t + 2 < ntiles) stageA(0, t + 2);
    __builtin_amdgcn_s_barrier();
    asm volatile("s_waitcnt lgkmcnt(0)" ::: "memory");
    __builtin_amdgcn_s_setprio(1);
    #pragma unroll
    for (int m = 0; m < 2; ++m)
      #pragma unroll
      for (int n = 0; n < 2; ++n)
        #pragma unroll
        for (int ks = 0; ks < 2; ++ks)
          acc[m][2+n] = __builtin_amdgcn_mfma_f32_16x16x32_bf16(
              af[m][ks], bf2[n][ks], acc[m][2+n], 0, 0, 0);
    __builtin_amdgcn_s_setprio(0);
    __builtin_amdgcn_s_barrier();

    // ---------- phase 3 ----------
    #pragma unroll
    for (int m = 0; m < 2; ++m)
      #pragma unroll
      for (int ks = 0; ks < 2; ++ks)
        af2[m][ks] = *(const bf16x8*)(lds + Ab + 2048 + offA[m][ks]);
    if (t + 2 < ntiles) stageB(0, t + 2);
    __builtin_amdgcn_s_barrier();
    asm volatile("s_waitcnt lgkmcnt(0)" ::: "memory");
    __builtin_amdgcn_s_setprio(1);
    #pragma unroll
    for (int m = 0; m < 2; ++m)
      #pragma unroll
      for (int n = 0; n < 2; ++n)
        #pragma unroll
        for (int ks = 0; ks < 2; ++ks)
          acc[2+m][2+n] = __builtin_amdgcn_mfma_f32_16x16x32_bf16(
              af2[m][ks], bf2[n][ks], acc[2+m][2+n], 0, 0, 0);
    __builtin_amdgcn_s_setprio(0);
    __builtin_amdgcn_s_barrier();

    // ---------- phase 4 ----------
    if (t + 2 < ntiles) stageB(1, t + 2);
    __builtin_amdgcn_s_barrier();
    __builtin_amdgcn_s_setprio(1);
    #pragma unroll
    for (int m = 0; m < 2; ++m)
      #pragma unroll
      for (int n = 0; n < 2; ++n)
        #pragma unroll
        for (int ks = 0; ks < 2; ++ks)
          acc[2+m][n] = __builtin_amdgcn_mfma_f32_16x16x32_bf16(
              af2[m][ks], bf[n][ks], acc[2+m][n], 0, 0, 0);
    __builtin_amdgcn_s_setprio(0);
    if (t + 2 < ntiles) { asm volatile("s_waitcnt vmcnt(5)" ::: "memory"); }
    else                { asm volatile("s_waitcnt vmcnt(0)" ::: "memory"); }
    __builtin_amdgcn_s_barrier();
  }

  #pragma unroll
  for (int mi = 0; mi < 4; ++mi) {
    const long row = arow0 + wr*64 + (mi >> 1)*32 + (mi & 1)*16 + lhi*4;
    #pragma unroll
    for (int ni = 0; ni < 4; ++ni) {
      const long col = brow0 + wc*64 + (ni >> 1)*32 + (ni & 1)*16 + l16;
      #pragma unroll
      for (int r = 0; r < 4; ++r)
        C[(row + r)*N + col] = acc[mi][ni][r];
    }
  }
}

// ---------------------------------------------------------------------------
// Fused per-head RMSNorm + RoPE for BOTH Q and K in one launch, in place.
// ---------------------------------------------------------------------------
__global__ __launch_bounds__(256) void norm_rope2(
    u16* __restrict__ Qb, u16* __restrict__ Kb,
    const float* __restrict__ qw, const float* __restrict__ kw,
    const int* __restrict__ pos)
{
  const int row  = blockIdx.x * 4 + (threadIdx.x >> 6);
  const int lane = threadIdx.x & 63;
  u16* p; const float* nw; float sc; int s;
  if (row < S_LEN*NHEADS) {
    p = Qb + (long)row * HD; nw = qw; sc = 0.08838834764831845f; s = row >> 5;
  } else {
    const int r2 = row - S_LEN*NHEADS;
    p = Kb + (long)r2 * HD; nw = kw; sc = 1.0f; s = r2 >> 3;
  }

  float x1 = __uint_as_float(((unsigned)p[lane]) << 16);
  float x2 = __uint_as_float(((unsigned)p[lane + 64]) << 16);
  float ss = x1*x1 + x2*x2;
  #pragma unroll
  for (int m = 32; m >= 1; m >>= 1) ss += __shfl_xor(ss, m);
  const float inv = rsqrtf(ss * (1.0f/128.0f) + 1e-6f);
  x1 *= inv * nw[lane];
  x2 *= inv * nw[lane + 64];

  const float inv_freq = expf(-(float)lane * (13.815510557964274f / 64.0f));
  const float ang = (float)pos[s] * inv_freq;
  float sn, cs;
  sincosf(ang, &sn, &cs);
  p[lane]      = f2bf((x1*cs - x2*sn) * sc);
  p[lane + 64] = f2bf((x2*cs + x1*sn) * sc);
}

// ---------------------------------------------------------------------------
// Causal flash attention — round-7 structure (XCD chunk + balanced T, best
// measured 120.6us) with ONE change: T14 async-STAGE split + T4 counted
// barriers. K/V staged global->REG (8x dwordx4, issued after barrier 1 so
// HBM/L2 latency hides under QK^T+softmax+PV), written to LDS at top of
// next iter via ds_write_b128. Raw s_barrier + lgkmcnt(0) only — NO
// vmcnt(0) drain at barriers, so stage loads stay in flight across them.
// LDS 40KB, 4 blocks/CU, 16 waves/CU preserved.
// ---------------------------------------------------------------------------
__global__ __launch_bounds__(256, 4) void attn(
    const u16* __restrict__ Q, const u16* __restrict__ K,
    const u16* __restrict__ VT, u16* __restrict__ O)
{
  __shared__ u16 Ks[64*128];   // [kv][d], XOR-swizzled cols
  __shared__ u16 Vt[128*64];   // [d][kv], XOR-swizzled cols
  __shared__ u16 Ps[4*16*64];  // per-wave P tile

  const int tid  = threadIdx.x;
  const int lane = tid & 63;
  const int w    = tid >> 6;
  const int l16  = lane & 15, lhi = lane >> 4;

  const int x8  = blockIdx.x & 7;        // XCD = kv-head group
  const int idx = blockIdx.x >> 3;       // [0,128) within chunk
  const int cc  = idx & 31;              // CU within XCD
  const int jj  = idx >> 5;              // head within group
  const int h   = x8*4 + jj;
  const int kh  = x8;                    // GQA 4:1
  const int T   = (jj & 1) ? cc : (NT - 1) - cc;
  const int qrow0 = T*64 + w*16;

  bf16x8 qf[4];
  #pragma unroll
  for (int ks = 0; ks < 4; ++ks)
    qf[ks] = *(const bf16x8*)(Q + (long)(qrow0 + l16)*QDIM + h*HD + ks*32 + lhi*8);

  // per-lane staging addresses (same swizzled layout the DMA version used)
  const u16* kbase[4]; int kld[4];
  const u16* vbase[4]; int vld[4];
  #pragma unroll
  for (int i = 0; i < 4; ++i) {
    const int r   = w*16 + i*4 + lhi;
    const int col = (l16*8) ^ ((r & 7) << 3);
    kbase[i] = K + (long)r*KVDIM + kh*HD + col;     // + t*64*KVDIM
    kld[i]   = (w*16 + i*4)*128 + lane*8;
  }
  #pragma unroll
  for (int i = 0; i < 4; ++i) {
    const int r   = w*32 + i*8 + (lane >> 3);
    const int col = ((lane & 7)*8) ^ ((r & 7) << 3);
    vbase[i] = VT + (long)(kh*HD + r)*S_LEN + col;  // + t*64
    vld[i]   = (w*32 + i*8)*64 + lane*8;
  }

  float mr[4] = {-1e30f,-1e30f,-1e30f,-1e30f};
  float lr[4] = {0.f,0.f,0.f,0.f};
  f32x4 of[8] = {};
  u16* Pw = Ps + w*16*64;

  // prologue: issue reg-stage loads for t=0
  u16x8 kreg[4], vreg[4];
  #pragma unroll
  for (int i = 0; i < 4; ++i) kreg[i] = *(const u16x8*)(kbase[i]);
  #pragma unroll
  for (int i = 0; i < 4; ++i) vreg[i] = *(const u16x8*)(vbase[i]);

  for (int t = 0; t <= T; ++t) {
    // ---- write staged regs -> LDS (compiler waits vmcnt per reg) ----
    #pragma unroll
    for (int i = 0; i < 4; ++i) *(u16x8*)(Ks + kld[i]) = kreg[i];
    #pragma unroll
    for (int i = 0; i < 4; ++i) *(u16x8*)(Vt + vld[i]) = vreg[i];
    asm volatile("s_waitcnt lgkmcnt(0)" ::: "memory");
    __builtin_amdgcn_s_barrier();

    // ---- issue stage loads for t+1 (hide under compute below) ----
    if (t < T) {
      const long ko = (long)(t + 1) * 64 * KVDIM;
      const int  vo = (t + 1) * 64;
      #pragma unroll
      for (int i = 0; i < 4; ++i) kreg[i] = *(const u16x8*)(kbase[i] + ko);
      #pragma unroll
      for (int i = 0; i < 4; ++i) vreg[i] = *(const u16x8*)(vbase[i] + vo);
    }

    const int kv0 = t * 64;

    // ---- QK^T ----
    f32x4 sa[4] = {};
    __builtin_amdgcn_s_setprio(1);
    #pragma unroll
    for (int n = 0; n < 4; ++n)
      #pragma unroll
      for (int ks = 0; ks < 4; ++ks) {
        bf16x8 kf = *(const bf16x8*)(
            Ks + (n*16 + l16)*128 + ((ks*32 + lhi*8) ^ ((l16 & 7) << 3)));
        sa[n] = __builtin_amdgcn_mfma_f32_16x16x32_bf16(qf[ks], kf, sa[n], 0, 0, 0);
      }
    __builtin_amdgcn_s_setprio(0);

    // ---- online softmax, defer-max (THR=8) ----
    const bool diag = (t == T);
    float pm[4];
    #pragma unroll
    for (int r = 0; r < 4; ++r) {
      const int grow = qrow0 + lhi*4 + r;
      #pragma unroll
      for (int n = 0; n < 4; ++n) {
        float sv = sa[n][r];
        if (diag && (kv0 + n*16 + l16 > grow)) sv = -1e9f;
        sa[n][r] = sv;
      }
      float p01 = fmaxf(sa[0][r], sa[1][r]);
      float p23 = fmaxf(sa[2][r], sa[3][r]);
      float pmx = fmaxf(p01, p23);
      pmx = fmaxf(pmx, __shfl_xor(pmx, 1));
      pmx = fmaxf(pmx, __shfl_xor(pmx, 2));
      pmx = fmaxf(pmx, __shfl_xor(pmx, 4));
      pmx = fmaxf(pmx, __shfl_xor(pmx, 8));
      pm[r] = pmx;
    }
    bool need = (pm[0] > mr[0] + 8.f) | (pm[1] > mr[1] + 8.f) |
                (pm[2] > mr[2] + 8.f) | (pm[3] > mr[3] + 8.f);
    if (__any(need)) {
      #pragma unroll
      for (int r = 0; r < 4; ++r) {
        const float mnew  = fmaxf(mr[r], pm[r]);
        const float alpha = __expf(mr[r] - mnew);
        mr[r] = mnew;
        lr[r] *= alpha;
        #pragma unroll
        for (int c = 0; c < 8; ++c) of[c][r] *= alpha;
      }
    }
    #pragma unroll
    for (int r = 0; r < 4; ++r) {
      float rsum = 0.f;
      #pragma unroll
      for (int n = 0; n < 4; ++n) {
        float pv = __expf(sa[n][r] - mr[r]);
        sa[n][r] = pv;
        rsum += pv;
      }
      rsum += __shfl_xor(rsum, 1);
      rsum += __shfl_xor(rsum, 2);
      rsum += __shfl_xor(rsum, 4);
      rsum += __shfl_xor(rsum, 8);
      lr[r] += rsum;
    }

    // ---- P -> LDS, PV ----
    #pragma unroll
    for (int r = 0; r < 4; ++r) {
      const int prow = lhi*4 + r;
      #pragma unroll
      for (int n = 0; n < 4; ++n)
        Pw[prow*64 + ((n*16 + l16) ^ ((prow & 7) << 3))] = f2bf(sa[n][r]);
    }
    __builtin_amdgcn_s_setprio(1);
    #pragma unroll
    for (int ks = 0; ks < 2; ++ks) {
      bf16x8 pf = *(const bf16x8*)(
          Pw + l16*64 + ((ks*32 + lhi*8) ^ ((l16 & 7) << 3)));
      #pragma unroll
      for (int c = 0; c < 8; ++c) {
        bf16x8 vf = *(const bf16x8*)(
            Vt + (c*16 + l16)*64 + ((ks*32 + lhi*8) ^ ((l16 & 7) << 3)));
        of[c] = __builtin_amdgcn_mfma_f32_16x16x32_bf16(pf, vf, of[c], 0, 0, 0);
      }
    }
    __builtin_amdgcn_s_setprio(0);
    // all LDS reads of this tile done -> safe to overwrite next iter
    asm volatile("s_waitcnt lgkmcnt(0)" ::: "memory");
    __builtin_amdgcn_s_barrier();
  }

  #pragma unroll
  for (int r = 0; r < 4; ++r) {
    const float invl = 1.0f / lr[r];
    const long orow = (long)(qrow0 + lhi*4 + r) * QDIM + h*HD;
    #pragma unroll
    for (int c = 0; c < 8; ++c)
      O[orow + c*16 + l16] = f2bf(of[c][r] * invl);
  }
}

// ---------------------------------------------------------------------------
extern "C" void kernel_launch(void* const* d_in, const int* in_sizes, int n_in,
                              void* d_out, int out_size, void* d_ws, size_t ws_size,
                              hipStream_t stream) {
  (void)in_sizes; (void)n_in; (void)out_size; (void)ws_size;
  const float* hs  = (const float*)d_in[0];
  const int*   pos = (const int*)d_in[1];
  const float* Wq  = (const float*)d_in[2];
  const float* Wk  = (const float*)d_in[3];
  const float* Wv  = (const float*)d_in[4];
  const float* Wo  = (const float*)d_in[5];
  const float* qw  = (const float*)d_in[6];
  const float* kw  = (const float*)d_in[7];

  // Workspace layout (bf16 u16 elements), total 88 MB:
  u16* hsB = (u16*)d_ws;                          // 2048*4096
  u16* W1  = hsB + (long)S_LEN*HID;               // 4096*4096 (Wq, later Wo)
  u16* WkB = W1  + (long)QDIM*HID;                // 1024*4096
  u16* WvB = WkB + (long)KVDIM*HID;               // 1024*4096
  u16* Kb  = WvB + (long)KVDIM*HID;               // 2048*1024
  u16* VT  = Kb  + (long)S_LEN*KVDIM;             // 1024*2048 (V transposed)
  u16* AO  = VT  + (long)KVDIM*S_LEN;             // 2048*4096
  u16* Qb  = (u16*)d_out;                         // 2048*4096 (dead before final GEMM)

  f2b4<<<4096, 256, 0, stream>>>(hs, hsB, (long)S_LEN*HID/8,
                                 Wq, W1,  (long)QDIM*HID/8,
                                 Wk, WkB, (long)KVDIM*HID/8,
                                 Wv, WvB, (long)KVDIM*HID/8);

  // fused Q+K+V projection: 256x192 tile, grid 32x8 = 256 blocks (1 round)
  gemmQ<HID><<<dim3((QDIM+2*KVDIM)/192, S_LEN/256), 512, 0, stream>>>(
      hsB, W1, Qb, Kb, VT);

  norm_rope2<<<(S_LEN*NHEADS + S_LEN*NKV)/4, 256, 0, stream>>>(
      Qb, Kb, qw, kw, pos);

  f2b<<<2048, 256, 0, stream>>>(Wo, W1, (long)HID*QDIM/8);

  // attention: 1024 blocks, XCD-chunk swizzled, balanced T per CU (r7 map)
  attn<<<dim3(NT*NHEADS), 256, 0, stream>>>(Qb, Kb, VT, AO);

  // final projection: 128x256 tile, 16x16 = 256 blocks (full machine)
  gemmF<HID, QDIM><<<dim3(HID/256, S_LEN/128), 512, 0, stream>>>(
      AO, W1, (float*)d_out);
}

// Round 12
// 330.782 us; speedup vs baseline: 1.4971x; 1.4971x over previous
//
#include <hip/hip_runtime.h>
#include <hip/hip_bf16.h>

typedef unsigned short u16;
typedef __bf16 bf16x8 __attribute__((ext_vector_type(8)));
typedef u16 u16x4 __attribute__((ext_vector_type(4)));
typedef u16 u16x8 __attribute__((ext_vector_type(8)));
typedef float f32x4 __attribute__((ext_vector_type(4)));

#define S_LEN  2048
#define HID    4096
#define NHEADS 32
#define NKV    8
#define HD     128
#define QDIM   (NHEADS*HD)   // 4096
#define KVDIM  (NKV*HD)      // 1024
#define NT     (S_LEN/64)    // 32 kv/q tiles

__device__ __forceinline__ u16 f2bf(float f) {
  unsigned u = __float_as_uint(f);
  u += 0x7fff + ((u >> 16) & 1);   // RNE
  return (u16)(u >> 16);
}
__device__ __forceinline__ void lds_load16(const u16* g, u16* l) {
  __builtin_amdgcn_global_load_lds(
      (__attribute__((address_space(1))) void*)(g),
      (__attribute__((address_space(3))) void*)(l), 16, 0, 0);
}

// ---------------------------------------------------------------------------
// Segmented fp32 -> bf16 bulk convert: 4 buffers in one launch. n = elems/8.
// ---------------------------------------------------------------------------
__global__ __launch_bounds__(256) void f2b4(
    const float* __restrict__ s0, u16* __restrict__ d0, long n0,
    const float* __restrict__ s1, u16* __restrict__ d1, long n1,
    const float* __restrict__ s2, u16* __restrict__ d2, long n2,
    const float* __restrict__ s3, u16* __restrict__ d3, long n3)
{
  const float* s; u16* d; long n; int b0, nb;
  const int b = blockIdx.x;
  if (b < 1024)      { s=s0; d=d0; n=n0; b0=0;    nb=1024; }
  else if (b < 3072) { s=s1; d=d1; n=n1; b0=1024; nb=2048; }
  else if (b < 3584) { s=s2; d=d2; n=n2; b0=3072; nb=512;  }
  else               { s=s3; d=d3; n=n3; b0=3584; nb=512;  }
  long i = (long)(b - b0)*256 + threadIdx.x;
  const long stride = (long)nb*256;
  for (; i < n; i += stride) {
    f32x4 a = ((const f32x4*)s)[i*2];
    f32x4 c = ((const f32x4*)s)[i*2 + 1];
    u16x8 o;
    #pragma unroll
    for (int j = 0; j < 4; ++j) { o[j] = f2bf(a[j]); o[4+j] = f2bf(c[j]); }
    ((u16x8*)d)[i] = o;
  }
}

__global__ __launch_bounds__(256) void f2b(
    const float* __restrict__ in, u16* __restrict__ out, long n8)
{
  long i = (long)blockIdx.x * blockDim.x + threadIdx.x;
  const long stride = (long)gridDim.x * blockDim.x;
  for (; i < n8; i += stride) {
    f32x4 a = ((const f32x4*)in)[i*2];
    f32x4 b = ((const f32x4*)in)[i*2 + 1];
    u16x8 o;
    #pragma unroll
    for (int j = 0; j < 4; ++j) { o[j] = f2bf(a[j]); o[4+j] = f2bf(b[j]); }
    ((u16x8*)out)[i] = o;
  }
}

// ---------------------------------------------------------------------------
// QKV projection GEMM, round-12: 128x192 tile -> grid 32x16 = 512 blocks =
// 2 blocks/CU (LDS 80KB/block), 16 waves/CU for cross-block stall overlap.
// Same 4-phase schedule/staging algebra as the verified 256x192 gemmQ:
// 8 waves 2Mx4N, per-wave 64x48, acc[4][3], counted vmcnt(3), G4 swizzle.
// A staged whole-tile at ph1 (2 loads); B part0 at ph2 (2), part1 at ph3 (1).
// Hazards: each staged region's readers drained >=1 barrier before its DMA
// issues (part0 read ph1 / written ph2; part1 read ph2 / written ph3; A(t+2)
// written ph1 of t+1 after tile-t reads done). vmcnt(3) at ph4 = the 3
// newest (B(t+2)) may fly; A(t+1)+B(t+1) landed.
// __launch_bounds__(512,4) caps 128 regs/wave for 2-block residency.
// ---------------------------------------------------------------------------
template<int K>
__global__ __launch_bounds__(512, 4) void gemmQ(
    const u16* __restrict__ A, const u16* __restrict__ B,
    u16* __restrict__ Cq, u16* __restrict__ Ck, u16* __restrict__ Cv)
{
  __shared__ u16 lds[40960];   // A: [0,16384) 2x8192; B: [16384,40960) 2x12288
  const int tid  = threadIdx.x;
  const int lane = tid & 63;
  const int w    = tid >> 6;
  const int wr   = w >> 2, wc = w & 3;
  const int l16  = lane & 15, lhi = lane >> 4;
  const long arow0 = (long)blockIdx.y * 128;
  const long brow0 = (long)blockIdx.x * 192;
  const int ntiles = K >> 6;

  const int cu = ((lane & 7) ^ (lane >> 3)) * 8;
  const int wl = w*8 + (lane >> 3);            // [0,64)
  const u16* Ag[2];
  #pragma unroll
  for (int r = 0; r < 2; ++r)
    Ag[r] = A + (arow0 + r*64 + wl)*(long)K + cu;
  const u16* Bg[3];
  #pragma unroll
  for (int r = 0; r < 2; ++r) {
    const int rp = r*64 + wl;
    Bg[r] = B + (brow0 + (rp >> 5)*48 + (rp & 31))*(long)K + cu;
  }
  Bg[2] = B + (brow0 + (wl >> 4)*48 + 32 + (wl & 15))*(long)K + cu;

  auto stageA = [&](int kt) {                  // whole A tile: rounds 0,1
    u16* d = lds + ((kt & 1) << 13) + w*512;
    lds_load16(Ag[0] + (long)kt*64, d);
    lds_load16(Ag[1] + (long)kt*64, d + 4096);
  };
  auto stageB0 = [&](int kt) {                 // B part0: rounds 0,1
    u16* d = lds + 16384 + (kt & 1)*12288 + w*512;
    lds_load16(Bg[0] + (long)kt*64, d);
    lds_load16(Bg[1] + (long)kt*64, d + 4096);
  };
  auto stageB1 = [&](int kt) {                 // B part1: round 2
    u16* d = lds + 16384 + (kt & 1)*12288 + w*512;
    lds_load16(Bg[2] + (long)kt*64, d + 8192);
  };

  const int xr = (l16 & 7) << 3;
  int offA[2][2], offB[2][2], offB2[2];
  #pragma unroll
  for (int m2 = 0; m2 < 2; ++m2)
    #pragma unroll
    for (int ks = 0; ks < 2; ++ks)
      offA[m2][ks] = (wr*64 + m2*16 + l16)*64 + ((ks*32 + lhi*8) ^ xr);
  #pragma unroll
  for (int n2 = 0; n2 < 2; ++n2)
    #pragma unroll
    for (int ks = 0; ks < 2; ++ks)
      offB[n2][ks] = (wc*32 + n2*16 + l16)*64 + ((ks*32 + lhi*8) ^ xr);
  #pragma unroll
  for (int ks = 0; ks < 2; ++ks)
    offB2[ks] = 8192 + (wc*16 + l16)*64 + ((ks*32 + lhi*8) ^ xr);

  f32x4 acc[4][3] = {};

  // prologue: t0 fully (5 loads), t1's B (3 loads; A(1) comes at ph1 of t0)
  stageA(0); stageB0(0); stageB1(0);
  stageB0(1); stageB1(1);
  asm volatile("s_waitcnt vmcnt(3)" ::: "memory");
  __builtin_amdgcn_s_barrier();

  #pragma unroll 2
  for (int t = 0; t < ntiles; ++t) {
    const int Ab = (t & 1) << 13;
    const int Bb = 16384 + (t & 1)*12288;
    bf16x8 af[2][2], af2[2][2], bf[2][2], bf2[2];

    // ---------- phase 1: A half0 x B part0 -> acc[0:2][0:2] ----------
    #pragma unroll
    for (int m2 = 0; m2 < 2; ++m2)
      #pragma unroll
      for (int ks = 0; ks < 2; ++ks)
        af[m2][ks] = *(const bf16x8*)(lds + Ab + offA[m2][ks]);
    #pragma unroll
    for (int n2 = 0; n2 < 2; ++n2)
      #pragma unroll
      for (int ks = 0; ks < 2; ++ks)
        bf[n2][ks] = *(const bf16x8*)(lds + Bb + offB[n2][ks]);
    if (t + 1 < ntiles) stageA(t + 1);
    __builtin_amdgcn_s_barrier();
    asm volatile("s_waitcnt lgkmcnt(0)" ::: "memory");
    __builtin_amdgcn_s_setprio(1);
    #pragma unroll
    for (int m2 = 0; m2 < 2; ++m2)
      #pragma unroll
      for (int n2 = 0; n2 < 2; ++n2)
        #pragma unroll
        for (int ks = 0; ks < 2; ++ks)
          acc[m2][n2] = __builtin_amdgcn_mfma_f32_16x16x32_bf16(
              af[m2][ks], bf[n2][ks], acc[m2][n2], 0, 0, 0);
    __builtin_amdgcn_s_setprio(0);
    __builtin_amdgcn_s_barrier();

    // ---------- phase 2: A half0 x B part1 -> acc[0:2][2] ----------
    #pragma unroll
    for (int ks = 0; ks < 2; ++ks)
      bf2[ks] = *(const bf16x8*)(lds + Bb + offB2[ks]);
    if (t + 2 < ntiles) stageB0(t + 2);
    __builtin_amdgcn_s_barrier();
    asm volatile("s_waitcnt lgkmcnt(0)" ::: "memory");
    __builtin_amdgcn_s_setprio(1);
    #pragma unroll
    for (int m2 = 0; m2 < 2; ++m2)
      #pragma unroll
      for (int ks = 0; ks < 2; ++ks)
        acc[m2][2] = __builtin_amdgcn_mfma_f32_16x16x32_bf16(
            af[m2][ks], bf2[ks], acc[m2][2], 0, 0, 0);
    __builtin_amdgcn_s_setprio(0);
    __builtin_amdgcn_s_barrier();

    // ---------- phase 3: A half1 x B part1 -> acc[2:4][2] ----------
    #pragma unroll
    for (int m2 = 0; m2 < 2; ++m2)
      #pragma unroll
      for (int ks = 0; ks < 2; ++ks)
        af2[m2][ks] = *(const bf16x8*)(lds + Ab + 2048 + offA[m2][ks]);
    if (t + 2 < ntiles) stageB1(t + 2);
    __builtin_amdgcn_s_barrier();
    asm volatile("s_waitcnt lgkmcnt(0)" ::: "memory");
    __builtin_amdgcn_s_setprio(1);
    #pragma unroll
    for (int m2 = 0; m2 < 2; ++m2)
      #pragma unroll
      for (int ks = 0; ks < 2; ++ks)
        acc[2+m2][2] = __builtin_amdgcn_mfma_f32_16x16x32_bf16(
            af2[m2][ks], bf2[ks], acc[2+m2][2], 0, 0, 0);
    __builtin_amdgcn_s_setprio(0);
    __builtin_amdgcn_s_barrier();

    // ---------- phase 4: A half1 x B part0 -> acc[2:4][0:2] ----------
    __builtin_amdgcn_s_setprio(1);
    #pragma unroll
    for (int m2 = 0; m2 < 2; ++m2)
      #pragma unroll
      for (int n2 = 0; n2 < 2; ++n2)
        #pragma unroll
        for (int ks = 0; ks < 2; ++ks)
          acc[2+m2][n2] = __builtin_amdgcn_mfma_f32_16x16x32_bf16(
              af2[m2][ks], bf[n2][ks], acc[2+m2][n2], 0, 0, 0);
    __builtin_amdgcn_s_setprio(0);
    if (t + 2 < ntiles) { asm volatile("s_waitcnt vmcnt(3)" ::: "memory"); }
    else                { asm volatile("s_waitcnt vmcnt(0)" ::: "memory"); }
    __builtin_amdgcn_s_barrier();
  }

  // epilogue: C/D layout col = lane&15, row = (lane>>4)*4 + reg
  #pragma unroll
  for (int m = 0; m < 4; ++m) {
    const long row = arow0 + wr*64 + m*16 + lhi*4;
    #pragma unroll
    for (int n = 0; n < 3; ++n) {
      const long col = brow0 + wc*48 + n*16 + l16;
      if (col < QDIM) {
        #pragma unroll
        for (int r = 0; r < 4; ++r)
          Cq[(row + r)*QDIM + col] = f2bf(acc[m][n][r]);
      } else if (col < QDIM + KVDIM) {
        #pragma unroll
        for (int r = 0; r < 4; ++r)
          Ck[(row + r)*KVDIM + (col - QDIM)] = f2bf(acc[m][n][r]);
      } else {
        u16x4 o;
        #pragma unroll
        for (int r = 0; r < 4; ++r) o[r] = f2bf(acc[m][n][r]);
        *(u16x4*)(Cv + (col - QDIM - KVDIM)*(long)S_LEN + row) = o;
      }
    }
  }
}

// ---------------------------------------------------------------------------
// 128x256-tile 4-phase GEMM for the final projection (verified rounds 2-11).
// ---------------------------------------------------------------------------
template<int N, int K>
__global__ __launch_bounds__(512, 2) void gemmF(
    const u16* __restrict__ A, const u16* __restrict__ B,
    float* __restrict__ C)
{
  __shared__ u16 lds[49152];   // A: [0,16384) 2x8192; B: [16384,49152) 2x16384
  const int tid  = threadIdx.x;
  const int lane = tid & 63;
  const int w    = tid >> 6;
  const int wr   = w >> 2, wc = w & 3;
  const int l16  = lane & 15, lhi = lane >> 4;
  const long arow0 = (long)blockIdx.y * 128;
  const long brow0 = (long)blockIdx.x * 256;
  const int ntiles = K >> 6;

  const int cu = ((lane & 7) ^ (lane >> 3)) * 8;
  const int rA  = (w >> 2)*64 + (w & 3)*8;
  const int rB1c = 128 + (w >> 2)*64 + (w & 3)*8;
  const u16* srcA  = A + (arow0 + rA   + (lane >> 3))*(long)K + cu;
  const u16* srcB0 = B + (brow0 + rA   + (lane >> 3))*(long)K + cu;
  const u16* srcB1 = B + (brow0 + rB1c + (lane >> 3))*(long)K + cu;
  u16* const dA  = lds + rA*64;
  u16* const dB0 = lds + 16384 + rA*64;
  u16* const dB1 = lds + 16384 + rB1c*64;

  auto stageA = [&](int s, int kt) {
    lds_load16(srcA + (long)(s*32)*K + kt*64,
               dA + ((kt & 1) << 13) + s*2048);
  };
  auto stageB = [&](int s, int kt) {
    const long so = (long)(s*32)*K + kt*64;
    const int  d  = ((kt & 1) << 14) + s*2048;
    lds_load16(srcB0 + so, dB0 + d);
    lds_load16(srcB1 + so, dB1 + d);
  };

  const int xr = (l16 & 7) << 3;
  int offA[2][2], offB[2][2];
  #pragma unroll
  for (int m = 0; m < 2; ++m)
    #pragma unroll
    for (int ks = 0; ks < 2; ++ks)
      offA[m][ks] = (wr*64 + m*16 + l16)*64 + ((ks*32 + lhi*8) ^ xr);
  #pragma unroll
  for (int n = 0; n < 2; ++n)
    #pragma unroll
    for (int ks = 0; ks < 2; ++ks)
      offB[n][ks] = (wc*64 + n*16 + l16)*64 + ((ks*32 + lhi*8) ^ xr);

  f32x4 acc[4][4] = {};

  stageA(0, 0); stageA(1, 0); stageB(0, 0); stageB(1, 0);
  if (ntiles > 1) { stageA(0, 1); stageB(0, 1); stageB(1, 1); }
  asm volatile("s_waitcnt vmcnt(5)" ::: "memory");
  __builtin_amdgcn_s_barrier();

  #pragma unroll 2
  for (int t = 0; t < ntiles; ++t) {
    const int Ab = (t & 1) << 13;
    const int Bb = 16384 + ((t & 1) << 14);
    bf16x8 af[2][2], bf[2][2], af2[2][2], bf2[2][2];

    // ---------- phase 1 ----------
    #pragma unroll
    for (int m = 0; m < 2; ++m)
      #pragma unroll
      for (int ks = 0; ks < 2; ++ks)
        af[m][ks] = *(const bf16x8*)(lds + Ab + offA[m][ks]);
    #pragma unroll
    for (int n = 0; n < 2; ++n)
      #pragma unroll
      for (int ks = 0; ks < 2; ++ks)
        bf[n][ks] = *(const bf16x8*)(lds + Bb + offB[n][ks]);
    if (t + 1 < ntiles) stageA(1, t + 1);
    __builtin_amdgcn_s_barrier();
    asm volatile("s_waitcnt lgkmcnt(0)" ::: "memory");
    __builtin_amdgcn_s_setprio(1);
    #pragma unroll
    for (int m = 0; m < 2; ++m)
      #pragma unroll
      for (int n = 0; n < 2; ++n)
        #pragma unroll
        for (int ks = 0; ks < 2; ++ks)
          acc[m][n] = __builtin_amdgcn_mfma_f32_16x16x32_bf16(
              af[m][ks], bf[n][ks], acc[m][n], 0, 0, 0);
    __builtin_amdgcn_s_setprio(0);
    __builtin_amdgcn_s_barrier();

    // ---------- phase 2 ----------
    #pragma unroll
    for (int n = 0; n < 2; ++n)
      #pragma unroll
      for (int ks = 0; ks < 2; ++ks)
        bf2[n][ks] = *(const bf16x8*)(lds + Bb + 2048 + offB[n][ks]);
    if (t + 2 < ntiles) stageA(0, t + 2);
    __builtin_amdgcn_s_barrier();
    asm volatile("s_waitcnt lgkmcnt(0)" ::: "memory");
    __builtin_amdgcn_s_setprio(1);
    #pragma unroll
    for (int m = 0; m < 2; ++m)
      #pragma unroll
      for (int n = 0; n < 2; ++n)
        #pragma unroll
        for (int ks = 0; ks < 2; ++ks)
          acc[m][2+n] = __builtin_amdgcn_mfma_f32_16x16x32_bf16(
              af[m][ks], bf2[n][ks], acc[m][2+n], 0, 0, 0);
    __builtin_amdgcn_s_setprio(0);
    __builtin_amdgcn_s_barrier();

    // ---------- phase 3 ----------
    #pragma unroll
    for (int m = 0; m < 2; ++m)
      #pragma unroll
      for (int ks = 0; ks < 2; ++ks)
        af2[m][ks] = *(const bf16x8*)(lds + Ab + 2048 + offA[m][ks]);
    if (t + 2 < ntiles) stageB(0, t + 2);
    __builtin_amdgcn_s_barrier();
    asm volatile("s_waitcnt lgkmcnt(0)" ::: "memory");
    __builtin_amdgcn_s_setprio(1);
    #pragma unroll
    for (int m = 0; m < 2; ++m)
      #pragma unroll
      for (int n = 0; n < 2; ++n)
        #pragma unroll
        for (int ks = 0; ks < 2; ++ks)
          acc[2+m][2+n] = __builtin_amdgcn_mfma_f32_16x16x32_bf16(
              af2[m][ks], bf2[n][ks], acc[2+m][2+n], 0, 0, 0);
    __builtin_amdgcn_s_setprio(0);
    __builtin_amdgcn_s_barrier();

    // ---------- phase 4 ----------
    if (t + 2 < ntiles) stageB(1, t + 2);
    __builtin_amdgcn_s_barrier();
    __builtin_amdgcn_s_setprio(1);
    #pragma unroll
    for (int m = 0; m < 2; ++m)
      #pragma unroll
      for (int n = 0; n < 2; ++n)
        #pragma unroll
        for (int ks = 0; ks < 2; ++ks)
          acc[2+m][n] = __builtin_amdgcn_mfma_f32_16x16x32_bf16(
              af2[m][ks], bf[n][ks], acc[2+m][n], 0, 0, 0);
    __builtin_amdgcn_s_setprio(0);
    if (t + 2 < ntiles) { asm volatile("s_waitcnt vmcnt(5)" ::: "memory"); }
    else                { asm volatile("s_waitcnt vmcnt(0)" ::: "memory"); }
    __builtin_amdgcn_s_barrier();
  }

  #pragma unroll
  for (int mi = 0; mi < 4; ++mi) {
    const long row = arow0 + wr*64 + (mi >> 1)*32 + (mi & 1)*16 + lhi*4;
    #pragma unroll
    for (int ni = 0; ni < 4; ++ni) {
      const long col = brow0 + wc*64 + (ni >> 1)*32 + (ni & 1)*16 + l16;
      #pragma unroll
      for (int r = 0; r < 4; ++r)
        C[(row + r)*N + col] = acc[mi][ni][r];
    }
  }
}

// ---------------------------------------------------------------------------
// Fused per-head RMSNorm + RoPE for BOTH Q and K in one launch, in place.
// ---------------------------------------------------------------------------
__global__ __launch_bounds__(256) void norm_rope2(
    u16* __restrict__ Qb, u16* __restrict__ Kb,
    const float* __restrict__ qw, const float* __restrict__ kw,
    const int* __restrict__ pos)
{
  const int row  = blockIdx.x * 4 + (threadIdx.x >> 6);
  const int lane = threadIdx.x & 63;
  u16* p; const float* nw; float sc; int s;
  if (row < S_LEN*NHEADS) {
    p = Qb + (long)row * HD; nw = qw; sc = 0.08838834764831845f; s = row >> 5;
  } else {
    const int r2 = row - S_LEN*NHEADS;
    p = Kb + (long)r2 * HD; nw = kw; sc = 1.0f; s = r2 >> 3;
  }

  float x1 = __uint_as_float(((unsigned)p[lane]) << 16);
  float x2 = __uint_as_float(((unsigned)p[lane + 64]) << 16);
  float ss = x1*x1 + x2*x2;
  #pragma unroll
  for (int m = 32; m >= 1; m >>= 1) ss += __shfl_xor(ss, m);
  const float inv = rsqrtf(ss * (1.0f/128.0f) + 1e-6f);
  x1 *= inv * nw[lane];
  x2 *= inv * nw[lane + 64];

  const float inv_freq = expf(-(float)lane * (13.815510557964274f / 64.0f));
  const float ang = (float)pos[s] * inv_freq;
  float sn, cs;
  sincosf(ang, &sn, &cs);
  p[lane]      = f2bf((x1*cs - x2*sn) * sc);
  p[lane + 64] = f2bf((x2*cs + x1*sn) * sc);
}

// ---------------------------------------------------------------------------
// Causal flash attention — EXACT round-7 kernel (best measured: 120.6 us).
// XCD chunk (FETCH 15.4MB) + balanced per-CU T assignment; DMA staging,
// 2 __syncthreads/tile, 40KB LDS, 4 blocks/CU, 16 waves/CU.
// ---------------------------------------------------------------------------
__global__ __launch_bounds__(256, 4) void attn(
    const u16* __restrict__ Q, const u16* __restrict__ K,
    const u16* __restrict__ VT, u16* __restrict__ O)
{
  __shared__ u16 Ks[64*128];   // [kv][d], XOR-swizzled cols
  __shared__ u16 Vt[128*64];   // [d][kv], XOR-swizzled cols
  __shared__ u16 Ps[4*16*64];  // per-wave P tile

  const int tid  = threadIdx.x;
  const int lane = tid & 63;
  const int w    = tid >> 6;
  const int l16  = lane & 15, lhi = lane >> 4;

  const int x8  = blockIdx.x & 7;        // XCD = kv-head group
  const int idx = blockIdx.x >> 3;       // [0,128) within chunk
  const int cc  = idx & 31;              // CU within XCD
  const int jj  = idx >> 5;              // head within group
  const int h   = x8*4 + jj;
  const int kh  = x8;                    // GQA 4:1
  const int T   = (jj & 1) ? cc : (NT - 1) - cc;
  const int qrow0 = T*64 + w*16;

  bf16x8 qf[4];
  #pragma unroll
  for (int ks = 0; ks < 4; ++ks)
    qf[ks] = *(const bf16x8*)(Q + (long)(qrow0 + l16)*QDIM + h*HD + ks*32 + lhi*8);

  float mr[4] = {-1e30f,-1e30f,-1e30f,-1e30f};
  float lr[4] = {0.f,0.f,0.f,0.f};
  f32x4 of[8] = {};
  u16* Pw = Ps + w*16*64;

  for (int t = 0; t <= T; ++t) {
    const int kv0 = t * 64;
    // stage K tile [64][128]
    #pragma unroll
    for (int i = 0; i < 4; ++i) {
      const int r   = w*16 + i*4 + lhi;
      const int col = (l16*8) ^ ((r & 7) << 3);
      lds_load16(K + (long)(kv0 + r)*KVDIM + kh*HD + col,
                 Ks + (w*16 + i*4)*128);
    }
    // stage V^T tile [128][64]
    #pragma unroll
    for (int i = 0; i < 4; ++i) {
      const int r   = w*32 + i*8 + (lane >> 3);
      const int col = ((lane & 7)*8) ^ ((r & 7) << 3);
      lds_load16(VT + (long)(kh*HD + r)*S_LEN + kv0 + col,
                 Vt + (w*32 + i*8)*64);
    }
    __syncthreads();

    // ---- QK^T ----
    f32x4 sa[4] = {};
    __builtin_amdgcn_s_setprio(1);
    #pragma unroll
    for (int n = 0; n < 4; ++n)
      #pragma unroll
      for (int ks = 0; ks < 4; ++ks) {
        bf16x8 kf = *(const bf16x8*)(
            Ks + (n*16 + l16)*128 + ((ks*32 + lhi*8) ^ ((l16 & 7) << 3)));
        sa[n] = __builtin_amdgcn_mfma_f32_16x16x32_bf16(qf[ks], kf, sa[n], 0, 0, 0);
      }
    __builtin_amdgcn_s_setprio(0);

    // ---- online softmax, defer-max (THR=8) ----
    const bool diag = (t == T);
    float pm[4];
    #pragma unroll
    for (int r = 0; r < 4; ++r) {
      const int grow = qrow0 + lhi*4 + r;
      #pragma unroll
      for (int n = 0; n < 4; ++n) {
        float sv = sa[n][r];
        if (diag && (kv0 + n*16 + l16 > grow)) sv = -1e9f;
        sa[n][r] = sv;
      }
      float p01 = fmaxf(sa[0][r], sa[1][r]);
      float p23 = fmaxf(sa[2][r], sa[3][r]);
      float pmx = fmaxf(p01, p23);
      pmx = fmaxf(pmx, __shfl_xor(pmx, 1));
      pmx = fmaxf(pmx, __shfl_xor(pmx, 2));
      pmx = fmaxf(pmx, __shfl_xor(pmx, 4));
      pmx = fmaxf(pmx, __shfl_xor(pmx, 8));
      pm[r] = pmx;
    }
    bool need = (pm[0] > mr[0] + 8.f) | (pm[1] > mr[1] + 8.f) |
                (pm[2] > mr[2] + 8.f) | (pm[3] > mr[3] + 8.f);
    if (__any(need)) {
      #pragma unroll
      for (int r = 0; r < 4; ++r) {
        const float mnew  = fmaxf(mr[r], pm[r]);
        const float alpha = __expf(mr[r] - mnew);
        mr[r] = mnew;
        lr[r] *= alpha;
        #pragma unroll
        for (int c = 0; c < 8; ++c) of[c][r] *= alpha;
      }
    }
    #pragma unroll
    for (int r = 0; r < 4; ++r) {
      float rsum = 0.f;
      #pragma unroll
      for (int n = 0; n < 4; ++n) {
        float pv = __expf(sa[n][r] - mr[r]);
        sa[n][r] = pv;
        rsum += pv;
      }
      rsum += __shfl_xor(rsum, 1);
      rsum += __shfl_xor(rsum, 2);
      rsum += __shfl_xor(rsum, 4);
      rsum += __shfl_xor(rsum, 8);
      lr[r] += rsum;
    }

    // ---- P -> LDS, PV ----
    #pragma unroll
    for (int r = 0; r < 4; ++r) {
      const int prow = lhi*4 + r;
      #pragma unroll
      for (int n = 0; n < 4; ++n)
        Pw[prow*64 + ((n*16 + l16) ^ ((prow & 7) << 3))] = f2bf(sa[n][r]);
    }
    __builtin_amdgcn_s_setprio(1);
    #pragma unroll
    for (int ks = 0; ks < 2; ++ks) {
      bf16x8 pf = *(const bf16x8*)(
          Pw + l16*64 + ((ks*32 + lhi*8) ^ ((l16 & 7) << 3)));
      #pragma unroll
      for (int c = 0; c < 8; ++c) {
        bf16x8 vf = *(const bf16x8*)(
            Vt + (c*16 + l16)*64 + ((ks*32 + lhi*8) ^ ((l16 & 7) << 3)));
        of[c] = __builtin_amdgcn_mfma_f32_16x16x32_bf16(pf, vf, of[c], 0, 0, 0);
      }
    }
    __builtin_amdgcn_s_setprio(0);
    __syncthreads();
  }

  #pragma unroll
  for (int r = 0; r < 4; ++r) {
    const float invl = 1.0f / lr[r];
    const long orow = (long)(qrow0 + lhi*4 + r) * QDIM + h*HD;
    #pragma unroll
    for (int c = 0; c < 8; ++c)
      O[orow + c*16 + l16] = f2bf(of[c][r] * invl);
  }
}

// ---------------------------------------------------------------------------
extern "C" void kernel_launch(void* const* d_in, const int* in_sizes, int n_in,
                              void* d_out, int out_size, void* d_ws, size_t ws_size,
                              hipStream_t stream) {
  (void)in_sizes; (void)n_in; (void)out_size; (void)ws_size;
  const float* hs  = (const float*)d_in[0];
  const int*   pos = (const int*)d_in[1];
  const float* Wq  = (const float*)d_in[2];
  const float* Wk  = (const float*)d_in[3];
  const float* Wv  = (const float*)d_in[4];
  const float* Wo  = (const float*)d_in[5];
  const float* qw  = (const float*)d_in[6];
  const float* kw  = (const float*)d_in[7];

  // Workspace layout (bf16 u16 elements), total 88 MB:
  u16* hsB = (u16*)d_ws;                          // 2048*4096
  u16* W1  = hsB + (long)S_LEN*HID;               // 4096*4096 (Wq, later Wo)
  u16* WkB = W1  + (long)QDIM*HID;                // 1024*4096
  u16* WvB = WkB + (long)KVDIM*HID;               // 1024*4096
  u16* Kb  = WvB + (long)KVDIM*HID;               // 2048*1024
  u16* VT  = Kb  + (long)S_LEN*KVDIM;             // 1024*2048 (V transposed)
  u16* AO  = VT  + (long)KVDIM*S_LEN;             // 2048*4096
  u16* Qb  = (u16*)d_out;                         // 2048*4096 (dead before final GEMM)

  f2b4<<<4096, 256, 0, stream>>>(hs, hsB, (long)S_LEN*HID/8,
                                 Wq, W1,  (long)QDIM*HID/8,
                                 Wk, WkB, (long)KVDIM*HID/8,
                                 Wv, WvB, (long)KVDIM*HID/8);

  // fused Q+K+V projection: 128x192 tile, grid 32x16 = 512 blocks (2/CU)
  gemmQ<HID><<<dim3((QDIM+2*KVDIM)/192, S_LEN/128), 512, 0, stream>>>(
      hsB, W1, Qb, Kb, VT);

  norm_rope2<<<(S_LEN*NHEADS + S_LEN*NKV)/4, 256, 0, stream>>>(
      Qb, Kb, qw, kw, pos);

  f2b<<<2048, 256, 0, stream>>>(Wo, W1, (long)HID*QDIM/8);

  // attention: 1024 blocks, XCD-chunk swizzled, balanced T per CU (r7 map)
  attn<<<dim3(NT*NHEADS), 256, 0, stream>>>(Qb, Kb, VT, AO);

  // final projection: 128x256 tile, 16x16 = 256 blocks (full machine)
  gemmF<HID, QDIM><<<dim3(HID/256, S_LEN/128), 512, 0, stream>>>(
      AO, W1, (float*)d_out);
}

// Round 13
// 328.537 us; speedup vs baseline: 1.5073x; 1.0068x over previous
//
#include <hip/hip_runtime.h>
#include <hip/hip_bf16.h>

typedef unsigned short u16;
typedef __bf16 bf16x8 __attribute__((ext_vector_type(8)));
typedef u16 u16x4 __attribute__((ext_vector_type(4)));
typedef u16 u16x8 __attribute__((ext_vector_type(8)));
typedef float f32x4 __attribute__((ext_vector_type(4)));

#define S_LEN  2048
#define HID    4096
#define NHEADS 32
#define NKV    8
#define HD     128
#define QDIM   (NHEADS*HD)   // 4096
#define KVDIM  (NKV*HD)      // 1024
#define NT     (S_LEN/64)    // 32 kv/q tiles

__device__ __forceinline__ u16 f2bf(float f) {
  unsigned u = __float_as_uint(f);
  u += 0x7fff + ((u >> 16) & 1);   // RNE
  return (u16)(u >> 16);
}
__device__ __forceinline__ void lds_load16(const u16* g, u16* l) {
  __builtin_amdgcn_global_load_lds(
      (__attribute__((address_space(1))) void*)(g),
      (__attribute__((address_space(3))) void*)(l), 16, 0, 0);
}

// ---------------------------------------------------------------------------
// Segmented fp32 -> bf16 bulk convert: 4 buffers in one launch. n = elems/8.
// ---------------------------------------------------------------------------
__global__ __launch_bounds__(256) void f2b4(
    const float* __restrict__ s0, u16* __restrict__ d0, long n0,
    const float* __restrict__ s1, u16* __restrict__ d1, long n1,
    const float* __restrict__ s2, u16* __restrict__ d2, long n2,
    const float* __restrict__ s3, u16* __restrict__ d3, long n3)
{
  const float* s; u16* d; long n; int b0, nb;
  const int b = blockIdx.x;
  if (b < 1024)      { s=s0; d=d0; n=n0; b0=0;    nb=1024; }
  else if (b < 3072) { s=s1; d=d1; n=n1; b0=1024; nb=2048; }
  else if (b < 3584) { s=s2; d=d2; n=n2; b0=3072; nb=512;  }
  else               { s=s3; d=d3; n=n3; b0=3584; nb=512;  }
  long i = (long)(b - b0)*256 + threadIdx.x;
  const long stride = (long)nb*256;
  for (; i < n; i += stride) {
    f32x4 a = ((const f32x4*)s)[i*2];
    f32x4 c = ((const f32x4*)s)[i*2 + 1];
    u16x8 o;
    #pragma unroll
    for (int j = 0; j < 4; ++j) { o[j] = f2bf(a[j]); o[4+j] = f2bf(c[j]); }
    ((u16x8*)d)[i] = o;
  }
}

// ---------------------------------------------------------------------------
// QKV projection GEMM: 128x192 tile, grid 32x16 = 512 blocks = 2/CU
// (verified round 12: ~102 us, cross-block stall overlap).
// ---------------------------------------------------------------------------
template<int K>
__global__ __launch_bounds__(512, 4) void gemmQ(
    const u16* __restrict__ A, const u16* __restrict__ B,
    u16* __restrict__ Cq, u16* __restrict__ Ck, u16* __restrict__ Cv)
{
  __shared__ u16 lds[40960];   // A: [0,16384) 2x8192; B: [16384,40960) 2x12288
  const int tid  = threadIdx.x;
  const int lane = tid & 63;
  const int w    = tid >> 6;
  const int wr   = w >> 2, wc = w & 3;
  const int l16  = lane & 15, lhi = lane >> 4;
  const long arow0 = (long)blockIdx.y * 128;
  const long brow0 = (long)blockIdx.x * 192;
  const int ntiles = K >> 6;

  const int cu = ((lane & 7) ^ (lane >> 3)) * 8;
  const int wl = w*8 + (lane >> 3);            // [0,64)
  const u16* Ag[2];
  #pragma unroll
  for (int r = 0; r < 2; ++r)
    Ag[r] = A + (arow0 + r*64 + wl)*(long)K + cu;
  const u16* Bg[3];
  #pragma unroll
  for (int r = 0; r < 2; ++r) {
    const int rp = r*64 + wl;
    Bg[r] = B + (brow0 + (rp >> 5)*48 + (rp & 31))*(long)K + cu;
  }
  Bg[2] = B + (brow0 + (wl >> 4)*48 + 32 + (wl & 15))*(long)K + cu;

  auto stageA = [&](int kt) {                  // whole A tile: rounds 0,1
    u16* d = lds + ((kt & 1) << 13) + w*512;
    lds_load16(Ag[0] + (long)kt*64, d);
    lds_load16(Ag[1] + (long)kt*64, d + 4096);
  };
  auto stageB0 = [&](int kt) {                 // B part0: rounds 0,1
    u16* d = lds + 16384 + (kt & 1)*12288 + w*512;
    lds_load16(Bg[0] + (long)kt*64, d);
    lds_load16(Bg[1] + (long)kt*64, d + 4096);
  };
  auto stageB1 = [&](int kt) {                 // B part1: round 2
    u16* d = lds + 16384 + (kt & 1)*12288 + w*512;
    lds_load16(Bg[2] + (long)kt*64, d + 8192);
  };

  const int xr = (l16 & 7) << 3;
  int offA[2][2], offB[2][2], offB2[2];
  #pragma unroll
  for (int m2 = 0; m2 < 2; ++m2)
    #pragma unroll
    for (int ks = 0; ks < 2; ++ks)
      offA[m2][ks] = (wr*64 + m2*16 + l16)*64 + ((ks*32 + lhi*8) ^ xr);
  #pragma unroll
  for (int n2 = 0; n2 < 2; ++n2)
    #pragma unroll
    for (int ks = 0; ks < 2; ++ks)
      offB[n2][ks] = (wc*32 + n2*16 + l16)*64 + ((ks*32 + lhi*8) ^ xr);
  #pragma unroll
  for (int ks = 0; ks < 2; ++ks)
    offB2[ks] = 8192 + (wc*16 + l16)*64 + ((ks*32 + lhi*8) ^ xr);

  f32x4 acc[4][3] = {};

  stageA(0); stageB0(0); stageB1(0);
  stageB0(1); stageB1(1);
  asm volatile("s_waitcnt vmcnt(3)" ::: "memory");
  __builtin_amdgcn_s_barrier();

  #pragma unroll 2
  for (int t = 0; t < ntiles; ++t) {
    const int Ab = (t & 1) << 13;
    const int Bb = 16384 + (t & 1)*12288;
    bf16x8 af[2][2], af2[2][2], bf[2][2], bf2[2];

    // ---------- phase 1: A half0 x B part0 -> acc[0:2][0:2] ----------
    #pragma unroll
    for (int m2 = 0; m2 < 2; ++m2)
      #pragma unroll
      for (int ks = 0; ks < 2; ++ks)
        af[m2][ks] = *(const bf16x8*)(lds + Ab + offA[m2][ks]);
    #pragma unroll
    for (int n2 = 0; n2 < 2; ++n2)
      #pragma unroll
      for (int ks = 0; ks < 2; ++ks)
        bf[n2][ks] = *(const bf16x8*)(lds + Bb + offB[n2][ks]);
    if (t + 1 < ntiles) stageA(t + 1);
    __builtin_amdgcn_s_barrier();
    asm volatile("s_waitcnt lgkmcnt(0)" ::: "memory");
    __builtin_amdgcn_s_setprio(1);
    #pragma unroll
    for (int m2 = 0; m2 < 2; ++m2)
      #pragma unroll
      for (int n2 = 0; n2 < 2; ++n2)
        #pragma unroll
        for (int ks = 0; ks < 2; ++ks)
          acc[m2][n2] = __builtin_amdgcn_mfma_f32_16x16x32_bf16(
              af[m2][ks], bf[n2][ks], acc[m2][n2], 0, 0, 0);
    __builtin_amdgcn_s_setprio(0);
    __builtin_amdgcn_s_barrier();

    // ---------- phase 2: A half0 x B part1 -> acc[0:2][2] ----------
    #pragma unroll
    for (int ks = 0; ks < 2; ++ks)
      bf2[ks] = *(const bf16x8*)(lds + Bb + offB2[ks]);
    if (t + 2 < ntiles) stageB0(t + 2);
    __builtin_amdgcn_s_barrier();
    asm volatile("s_waitcnt lgkmcnt(0)" ::: "memory");
    __builtin_amdgcn_s_setprio(1);
    #pragma unroll
    for (int m2 = 0; m2 < 2; ++m2)
      #pragma unroll
      for (int ks = 0; ks < 2; ++ks)
        acc[m2][2] = __builtin_amdgcn_mfma_f32_16x16x32_bf16(
            af[m2][ks], bf2[ks], acc[m2][2], 0, 0, 0);
    __builtin_amdgcn_s_setprio(0);
    __builtin_amdgcn_s_barrier();

    // ---------- phase 3: A half1 x B part1 -> acc[2:4][2] ----------
    #pragma unroll
    for (int m2 = 0; m2 < 2; ++m2)
      #pragma unroll
      for (int ks = 0; ks < 2; ++ks)
        af2[m2][ks] = *(const bf16x8*)(lds + Ab + 2048 + offA[m2][ks]);
    if (t + 2 < ntiles) stageB1(t + 2);
    __builtin_amdgcn_s_barrier();
    asm volatile("s_waitcnt lgkmcnt(0)" ::: "memory");
    __builtin_amdgcn_s_setprio(1);
    #pragma unroll
    for (int m2 = 0; m2 < 2; ++m2)
      #pragma unroll
      for (int ks = 0; ks < 2; ++ks)
        acc[2+m2][2] = __builtin_amdgcn_mfma_f32_16x16x32_bf16(
            af2[m2][ks], bf2[ks], acc[2+m2][2], 0, 0, 0);
    __builtin_amdgcn_s_setprio(0);
    __builtin_amdgcn_s_barrier();

    // ---------- phase 4: A half1 x B part0 -> acc[2:4][0:2] ----------
    __builtin_amdgcn_s_setprio(1);
    #pragma unroll
    for (int m2 = 0; m2 < 2; ++m2)
      #pragma unroll
      for (int n2 = 0; n2 < 2; ++n2)
        #pragma unroll
        for (int ks = 0; ks < 2; ++ks)
          acc[2+m2][n2] = __builtin_amdgcn_mfma_f32_16x16x32_bf16(
              af2[m2][ks], bf[n2][ks], acc[2+m2][n2], 0, 0, 0);
    __builtin_amdgcn_s_setprio(0);
    if (t + 2 < ntiles) { asm volatile("s_waitcnt vmcnt(3)" ::: "memory"); }
    else                { asm volatile("s_waitcnt vmcnt(0)" ::: "memory"); }
    __builtin_amdgcn_s_barrier();
  }

  // epilogue: C/D layout col = lane&15, row = (lane>>4)*4 + reg
  #pragma unroll
  for (int m = 0; m < 4; ++m) {
    const long row = arow0 + wr*64 + m*16 + lhi*4;
    #pragma unroll
    for (int n = 0; n < 3; ++n) {
      const long col = brow0 + wc*48 + n*16 + l16;
      if (col < QDIM) {
        #pragma unroll
        for (int r = 0; r < 4; ++r)
          Cq[(row + r)*QDIM + col] = f2bf(acc[m][n][r]);
      } else if (col < QDIM + KVDIM) {
        #pragma unroll
        for (int r = 0; r < 4; ++r)
          Ck[(row + r)*KVDIM + (col - QDIM)] = f2bf(acc[m][n][r]);
      } else {
        u16x4 o;
        #pragma unroll
        for (int r = 0; r < 4; ++r) o[r] = f2bf(acc[m][n][r]);
        *(u16x4*)(Cv + (col - QDIM - KVDIM)*(long)S_LEN + row) = o;
      }
    }
  }
}

// ---------------------------------------------------------------------------
// Final projection GEMM, round-13: 128x128 tile -> grid 32x16 = 512 blocks
// = 2 blocks/CU (LDS 64KB/block). Mirror of the verified gemmQ algebra:
// 8 waves 2Mx4N, per-wave 64x32, acc[4][2]. A whole-tile staged at ph1
// (2 loads); B part0 (rows wc*32+[0,16), stripe map (wl>>4)*32+(wl&15))
// at ph2 (1 load); B part1 (+16) at ph3 (1 load). vmcnt(2) at ph4 =
// B(t+2)'s 2 newest in flight, A(t+1)+B(t+1) landed. fp32 row-major C.
// ---------------------------------------------------------------------------
template<int N, int K>
__global__ __launch_bounds__(512, 4) void gemmF(
    const u16* __restrict__ A, const u16* __restrict__ B,
    float* __restrict__ C)
{
  __shared__ u16 lds[32768];   // A: [0,16384) 2x8192; B: [16384,32768) 2x8192
  const int tid  = threadIdx.x;
  const int lane = tid & 63;
  const int w    = tid >> 6;
  const int wr   = w >> 2, wc = w & 3;
  const int l16  = lane & 15, lhi = lane >> 4;
  const long arow0 = (long)blockIdx.y * 128;
  const long brow0 = (long)blockIdx.x * 128;
  const int ntiles = K >> 6;

  const int cu = ((lane & 7) ^ (lane >> 3)) * 8;
  const int wl = w*8 + (lane >> 3);            // [0,64)
  const u16* Ag[2];
  #pragma unroll
  for (int r = 0; r < 2; ++r)
    Ag[r] = A + (arow0 + r*64 + wl)*(long)K + cu;
  const u16* Bg0 = B + (brow0 + (wl >> 4)*32      + (wl & 15))*(long)K + cu;
  const u16* Bg1 = B + (brow0 + (wl >> 4)*32 + 16 + (wl & 15))*(long)K + cu;

  auto stageA = [&](int kt) {                  // whole A tile: 2 rounds
    u16* d = lds + ((kt & 1) << 13) + w*512;
    lds_load16(Ag[0] + (long)kt*64, d);
    lds_load16(Ag[1] + (long)kt*64, d + 4096);
  };
  auto stageB0 = [&](int kt) {                 // B part0: 1 round
    lds_load16(Bg0 + (long)kt*64, lds + 16384 + ((kt & 1) << 13) + w*512);
  };
  auto stageB1 = [&](int kt) {                 // B part1: 1 round
    lds_load16(Bg1 + (long)kt*64, lds + 16384 + ((kt & 1) << 13) + 4096 + w*512);
  };

  const int xr = (l16 & 7) << 3;
  int offA[2][2], offB[2], offB2[2];
  #pragma unroll
  for (int m2 = 0; m2 < 2; ++m2)
    #pragma unroll
    for (int ks = 0; ks < 2; ++ks)
      offA[m2][ks] = (wr*64 + m2*16 + l16)*64 + ((ks*32 + lhi*8) ^ xr);
  #pragma unroll
  for (int ks = 0; ks < 2; ++ks) {
    offB[ks]  = (wc*16 + l16)*64 + ((ks*32 + lhi*8) ^ xr);
    offB2[ks] = 4096 + offB[ks];
  }

  f32x4 acc[4][2] = {};

  // prologue: tile0 fully (4 loads), tile1's B (2 loads)
  stageA(0); stageB0(0); stageB1(0);
  stageB0(1); stageB1(1);
  asm volatile("s_waitcnt vmcnt(2)" ::: "memory");
  __builtin_amdgcn_s_barrier();

  #pragma unroll 2
  for (int t = 0; t < ntiles; ++t) {
    const int Ab = (t & 1) << 13;
    const int Bb = 16384 + ((t & 1) << 13);
    bf16x8 af[2][2], af2[2][2], bf[2], bf2[2];

    // ---------- phase 1: A half0 x B part0 -> acc[0:2][0] ----------
    #pragma unroll
    for (int m2 = 0; m2 < 2; ++m2)
      #pragma unroll
      for (int ks = 0; ks < 2; ++ks)
        af[m2][ks] = *(const bf16x8*)(lds + Ab + offA[m2][ks]);
    #pragma unroll
    for (int ks = 0; ks < 2; ++ks)
      bf[ks] = *(const bf16x8*)(lds + Bb + offB[ks]);
    if (t + 1 < ntiles) stageA(t + 1);
    __builtin_amdgcn_s_barrier();
    asm volatile("s_waitcnt lgkmcnt(0)" ::: "memory");
    __builtin_amdgcn_s_setprio(1);
    #pragma unroll
    for (int m2 = 0; m2 < 2; ++m2)
      #pragma unroll
      for (int ks = 0; ks < 2; ++ks)
        acc[m2][0] = __builtin_amdgcn_mfma_f32_16x16x32_bf16(
            af[m2][ks], bf[ks], acc[m2][0], 0, 0, 0);
    __builtin_amdgcn_s_setprio(0);
    __builtin_amdgcn_s_barrier();

    // ---------- phase 2: A half0 x B part1 -> acc[0:2][1] ----------
    #pragma unroll
    for (int ks = 0; ks < 2; ++ks)
      bf2[ks] = *(const bf16x8*)(lds + Bb + offB2[ks]);
    if (t + 2 < ntiles) stageB0(t + 2);
    __builtin_amdgcn_s_barrier();
    asm volatile("s_waitcnt lgkmcnt(0)" ::: "memory");
    __builtin_amdgcn_s_setprio(1);
    #pragma unroll
    for (int m2 = 0; m2 < 2; ++m2)
      #pragma unroll
      for (int ks = 0; ks < 2; ++ks)
        acc[m2][1] = __builtin_amdgcn_mfma_f32_16x16x32_bf16(
            af[m2][ks], bf2[ks], acc[m2][1], 0, 0, 0);
    __builtin_amdgcn_s_setprio(0);
    __builtin_amdgcn_s_barrier();

    // ---------- phase 3: A half1 x B part1 -> acc[2:4][1] ----------
    #pragma unroll
    for (int m2 = 0; m2 < 2; ++m2)
      #pragma unroll
      for (int ks = 0; ks < 2; ++ks)
        af2[m2][ks] = *(const bf16x8*)(lds + Ab + 2048 + offA[m2][ks]);
    if (t + 2 < ntiles) stageB1(t + 2);
    __builtin_amdgcn_s_barrier();
    asm volatile("s_waitcnt lgkmcnt(0)" ::: "memory");
    __builtin_amdgcn_s_setprio(1);
    #pragma unroll
    for (int m2 = 0; m2 < 2; ++m2)
      #pragma unroll
      for (int ks = 0; ks < 2; ++ks)
        acc[2+m2][1] = __builtin_amdgcn_mfma_f32_16x16x32_bf16(
            af2[m2][ks], bf2[ks], acc[2+m2][1], 0, 0, 0);
    __builtin_amdgcn_s_setprio(0);
    __builtin_amdgcn_s_barrier();

    // ---------- phase 4: A half1 x B part0 -> acc[2:4][0] ----------
    __builtin_amdgcn_s_setprio(1);
    #pragma unroll
    for (int m2 = 0; m2 < 2; ++m2)
      #pragma unroll
      for (int ks = 0; ks < 2; ++ks)
        acc[2+m2][0] = __builtin_amdgcn_mfma_f32_16x16x32_bf16(
            af2[m2][ks], bf[ks], acc[2+m2][0], 0, 0, 0);
    __builtin_amdgcn_s_setprio(0);
    if (t + 2 < ntiles) { asm volatile("s_waitcnt vmcnt(2)" ::: "memory"); }
    else                { asm volatile("s_waitcnt vmcnt(0)" ::: "memory"); }
    __builtin_amdgcn_s_barrier();
  }

  // epilogue: row = arow0 + wr*64 + m*16 + lhi*4, col = brow0 + wc*32 + n*16 + l16
  #pragma unroll
  for (int m = 0; m < 4; ++m) {
    const long row = arow0 + wr*64 + m*16 + lhi*4;
    #pragma unroll
    for (int n = 0; n < 2; ++n) {
      const long col = brow0 + wc*32 + n*16 + l16;
      #pragma unroll
      for (int r = 0; r < 4; ++r)
        C[(row + r)*N + col] = acc[m][n][r];
    }
  }
}

// ---------------------------------------------------------------------------
// Fused per-head RMSNorm + RoPE for BOTH Q and K in one launch, in place.
// ---------------------------------------------------------------------------
__global__ __launch_bounds__(256) void norm_rope2(
    u16* __restrict__ Qb, u16* __restrict__ Kb,
    const float* __restrict__ qw, const float* __restrict__ kw,
    const int* __restrict__ pos)
{
  const int row  = blockIdx.x * 4 + (threadIdx.x >> 6);
  const int lane = threadIdx.x & 63;
  u16* p; const float* nw; float sc; int s;
  if (row < S_LEN*NHEADS) {
    p = Qb + (long)row * HD; nw = qw; sc = 0.08838834764831845f; s = row >> 5;
  } else {
    const int r2 = row - S_LEN*NHEADS;
    p = Kb + (long)r2 * HD; nw = kw; sc = 1.0f; s = r2 >> 3;
  }

  float x1 = __uint_as_float(((unsigned)p[lane]) << 16);
  float x2 = __uint_as_float(((unsigned)p[lane + 64]) << 16);
  float ss = x1*x1 + x2*x2;
  #pragma unroll
  for (int m = 32; m >= 1; m >>= 1) ss += __shfl_xor(ss, m);
  const float inv = rsqrtf(ss * (1.0f/128.0f) + 1e-6f);
  x1 *= inv * nw[lane];
  x2 *= inv * nw[lane + 64];

  const float inv_freq = expf(-(float)lane * (13.815510557964274f / 64.0f));
  const float ang = (float)pos[s] * inv_freq;
  float sn, cs;
  sincosf(ang, &sn, &cs);
  p[lane]      = f2bf((x1*cs - x2*sn) * sc);
  p[lane + 64] = f2bf((x2*cs + x1*sn) * sc);
}

// ---------------------------------------------------------------------------
// Causal flash attention — EXACT round-7/12 kernel (120.3 us) + fused Wo
// fp32->bf16 convert in the tail (attn runs at 4% HBM BW; W1 is dead after
// gemmQ and read next by gemmF, so the convert streams in attn's shadow).
// ---------------------------------------------------------------------------
__global__ __launch_bounds__(256, 4) void attn(
    const u16* __restrict__ Q, const u16* __restrict__ K,
    const u16* __restrict__ VT, u16* __restrict__ O,
    const float* __restrict__ Wo, u16* __restrict__ W1)
{
  __shared__ u16 Ks[64*128];   // [kv][d], XOR-swizzled cols
  __shared__ u16 Vt[128*64];   // [d][kv], XOR-swizzled cols
  __shared__ u16 Ps[4*16*64];  // per-wave P tile

  const int tid  = threadIdx.x;
  const int lane = tid & 63;
  const int w    = tid >> 6;
  const int l16  = lane & 15, lhi = lane >> 4;

  const int x8  = blockIdx.x & 7;        // XCD = kv-head group
  const int idx = blockIdx.x >> 3;       // [0,128) within chunk
  const int cc  = idx & 31;              // CU within XCD
  const int jj  = idx >> 5;              // head within group
  const int h   = x8*4 + jj;
  const int kh  = x8;                    // GQA 4:1
  const int T   = (jj & 1) ? cc : (NT - 1) - cc;
  const int qrow0 = T*64 + w*16;

  bf16x8 qf[4];
  #pragma unroll
  for (int ks = 0; ks < 4; ++ks)
    qf[ks] = *(const bf16x8*)(Q + (long)(qrow0 + l16)*QDIM + h*HD + ks*32 + lhi*8);

  float mr[4] = {-1e30f,-1e30f,-1e30f,-1e30f};
  float lr[4] = {0.f,0.f,0.f,0.f};
  f32x4 of[8] = {};
  u16* Pw = Ps + w*16*64;

  for (int t = 0; t <= T; ++t) {
    const int kv0 = t * 64;
    // stage K tile [64][128]
    #pragma unroll
    for (int i = 0; i < 4; ++i) {
      const int r   = w*16 + i*4 + lhi;
      const int col = (l16*8) ^ ((r & 7) << 3);
      lds_load16(K + (long)(kv0 + r)*KVDIM + kh*HD + col,
                 Ks + (w*16 + i*4)*128);
    }
    // stage V^T tile [128][64]
    #pragma unroll
    for (int i = 0; i < 4; ++i) {
      const int r   = w*32 + i*8 + (lane >> 3);
      const int col = ((lane & 7)*8) ^ ((r & 7) << 3);
      lds_load16(VT + (long)(kh*HD + r)*S_LEN + kv0 + col,
                 Vt + (w*32 + i*8)*64);
    }
    __syncthreads();

    // ---- QK^T ----
    f32x4 sa[4] = {};
    __builtin_amdgcn_s_setprio(1);
    #pragma unroll
    for (int n = 0; n < 4; ++n)
      #pragma unroll
      for (int ks = 0; ks < 4; ++ks) {
        bf16x8 kf = *(const bf16x8*)(
            Ks + (n*16 + l16)*128 + ((ks*32 + lhi*8) ^ ((l16 & 7) << 3)));
        sa[n] = __builtin_amdgcn_mfma_f32_16x16x32_bf16(qf[ks], kf, sa[n], 0, 0, 0);
      }
    __builtin_amdgcn_s_setprio(0);

    // ---- online softmax, defer-max (THR=8) ----
    const bool diag = (t == T);
    float pm[4];
    #pragma unroll
    for (int r = 0; r < 4; ++r) {
      const int grow = qrow0 + lhi*4 + r;
      #pragma unroll
      for (int n = 0; n < 4; ++n) {
        float sv = sa[n][r];
        if (diag && (kv0 + n*16 + l16 > grow)) sv = -1e9f;
        sa[n][r] = sv;
      }
      float p01 = fmaxf(sa[0][r], sa[1][r]);
      float p23 = fmaxf(sa[2][r], sa[3][r]);
      float pmx = fmaxf(p01, p23);
      pmx = fmaxf(pmx, __shfl_xor(pmx, 1));
      pmx = fmaxf(pmx, __shfl_xor(pmx, 2));
      pmx = fmaxf(pmx, __shfl_xor(pmx, 4));
      pmx = fmaxf(pmx, __shfl_xor(pmx, 8));
      pm[r] = pmx;
    }
    bool need = (pm[0] > mr[0] + 8.f) | (pm[1] > mr[1] + 8.f) |
                (pm[2] > mr[2] + 8.f) | (pm[3] > mr[3] + 8.f);
    if (__any(need)) {
      #pragma unroll
      for (int r = 0; r < 4; ++r) {
        const float mnew  = fmaxf(mr[r], pm[r]);
        const float alpha = __expf(mr[r] - mnew);
        mr[r] = mnew;
        lr[r] *= alpha;
        #pragma unroll
        for (int c = 0; c < 8; ++c) of[c][r] *= alpha;
      }
    }
    #pragma unroll
    for (int r = 0; r < 4; ++r) {
      float rsum = 0.f;
      #pragma unroll
      for (int n = 0; n < 4; ++n) {
        float pv = __expf(sa[n][r] - mr[r]);
        sa[n][r] = pv;
        rsum += pv;
      }
      rsum += __shfl_xor(rsum, 1);
      rsum += __shfl_xor(rsum, 2);
      rsum += __shfl_xor(rsum, 4);
      rsum += __shfl_xor(rsum, 8);
      lr[r] += rsum;
    }

    // ---- P -> LDS, PV ----
    #pragma unroll
    for (int r = 0; r < 4; ++r) {
      const int prow = lhi*4 + r;
      #pragma unroll
      for (int n = 0; n < 4; ++n)
        Pw[prow*64 + ((n*16 + l16) ^ ((prow & 7) << 3))] = f2bf(sa[n][r]);
    }
    __builtin_amdgcn_s_setprio(1);
    #pragma unroll
    for (int ks = 0; ks < 2; ++ks) {
      bf16x8 pf = *(const bf16x8*)(
          Pw + l16*64 + ((ks*32 + lhi*8) ^ ((l16 & 7) << 3)));
      #pragma unroll
      for (int c = 0; c < 8; ++c) {
        bf16x8 vf = *(const bf16x8*)(
            Vt + (c*16 + l16)*64 + ((ks*32 + lhi*8) ^ ((l16 & 7) << 3)));
        of[c] = __builtin_amdgcn_mfma_f32_16x16x32_bf16(pf, vf, of[c], 0, 0, 0);
      }
    }
    __builtin_amdgcn_s_setprio(0);
    __syncthreads();
  }

  #pragma unroll
  for (int r = 0; r < 4; ++r) {
    const float invl = 1.0f / lr[r];
    const long orow = (long)(qrow0 + lhi*4 + r) * QDIM + h*HD;
    #pragma unroll
    for (int c = 0; c < 8; ++c)
      O[orow + c*16 + l16] = f2bf(of[c][r] * invl);
  }

  // ---- fused Wo fp32 -> bf16 convert (8 grid-stride iters/thread) ----
  {
    const long n8 = (long)HID*QDIM/8;
    long i = (long)blockIdx.x*256 + tid;
    const long stride = (long)NT*NHEADS*256;
    for (; i < n8; i += stride) {
      f32x4 a = ((const f32x4*)Wo)[i*2];
      f32x4 b = ((const f32x4*)Wo)[i*2 + 1];
      u16x8 o;
      #pragma unroll
      for (int j = 0; j < 4; ++j) { o[j] = f2bf(a[j]); o[4+j] = f2bf(b[j]); }
      ((u16x8*)W1)[i] = o;
    }
  }
}

// ---------------------------------------------------------------------------
extern "C" void kernel_launch(void* const* d_in, const int* in_sizes, int n_in,
                              void* d_out, int out_size, void* d_ws, size_t ws_size,
                              hipStream_t stream) {
  (void)in_sizes; (void)n_in; (void)out_size; (void)ws_size;
  const float* hs  = (const float*)d_in[0];
  const int*   pos = (const int*)d_in[1];
  const float* Wq  = (const float*)d_in[2];
  const float* Wk  = (const float*)d_in[3];
  const float* Wv  = (const float*)d_in[4];
  const float* Wo  = (const float*)d_in[5];
  const float* qw  = (const float*)d_in[6];
  const float* kw  = (const float*)d_in[7];

  // Workspace layout (bf16 u16 elements), total 88 MB:
  u16* hsB = (u16*)d_ws;                          // 2048*4096
  u16* W1  = hsB + (long)S_LEN*HID;               // 4096*4096 (Wq, later Wo)
  u16* WkB = W1  + (long)QDIM*HID;                // 1024*4096
  u16* WvB = WkB + (long)KVDIM*HID;               // 1024*4096
  u16* Kb  = WvB + (long)KVDIM*HID;               // 2048*1024
  u16* VT  = Kb  + (long)S_LEN*KVDIM;             // 1024*2048 (V transposed)
  u16* AO  = VT  + (long)KVDIM*S_LEN;             // 2048*4096
  u16* Qb  = (u16*)d_out;                         // 2048*4096 (dead before final GEMM)

  f2b4<<<4096, 256, 0, stream>>>(hs, hsB, (long)S_LEN*HID/8,
                                 Wq, W1,  (long)QDIM*HID/8,
                                 Wk, WkB, (long)KVDIM*HID/8,
                                 Wv, WvB, (long)KVDIM*HID/8);

  // fused Q+K+V projection: 128x192 tile, grid 32x16 = 512 blocks (2/CU)
  gemmQ<HID><<<dim3((QDIM+2*KVDIM)/192, S_LEN/128), 512, 0, stream>>>(
      hsB, W1, Qb, Kb, VT);

  norm_rope2<<<(S_LEN*NHEADS + S_LEN*NKV)/4, 256, 0, stream>>>(
      Qb, Kb, qw, kw, pos);

  // attention (+ fused Wo convert): 1024 blocks, XCD-chunked, balanced T
  attn<<<dim3(NT*NHEADS), 256, 0, stream>>>(Qb, Kb, VT, AO, Wo, W1);

  // final projection: 128x128 tile, grid 32x16 = 512 blocks (2/CU)
  gemmF<HID, QDIM><<<dim3(HID/128, S_LEN/128), 512, 0, stream>>>(
      AO, W1, (float*)d_out);
}